// Round 3
// baseline (1755.128 us; speedup 1.0000x reference)
//
#include <hip/hip_runtime.h>
#include <hip/hip_bf16.h>
#include <stdint.h>
#include <stddef.h>

#define N_NODES 100000
#define N_EDGES 1600000
#define FEAT 128
#define NB_SCAN ((N_NODES + 255) / 256)   // 391 blocks of 256 for the scan

typedef __attribute__((ext_vector_type(8))) short bf16x8;
typedef __attribute__((ext_vector_type(4))) float f32x4;
typedef unsigned short u16;

__device__ __forceinline__ float bf2f(u16 u) {
    union { unsigned int i; float f; } v; v.i = ((unsigned int)u) << 16; return v.f;
}
__device__ __forceinline__ u16 f2bf(float f) {
    union { float f; unsigned int i; } v; v.f = f;
    unsigned int x = v.i;
    return (u16)((x + 0x7fffu + ((x >> 16) & 1u)) >> 16);   // round-nearest-even
}

// ---------------- CSR build ----------------

__global__ void hist_kernel(const int* __restrict__ rows, int* __restrict__ counts) {
    int e = blockIdx.x * blockDim.x + threadIdx.x;
    if (e < N_EDGES) {
        int r = rows[e];
        r = min(max(r, 0), N_NODES - 1);
        atomicAdd(&counts[r], 1);
    }
}

__global__ void reduce_counts_kernel(const int* __restrict__ counts, int* __restrict__ bsum) {
    __shared__ int s[256];
    int i = blockIdx.x * 256 + threadIdx.x;
    int v = (i < N_NODES) ? counts[i] : 0;
    s[threadIdx.x] = v; __syncthreads();
    for (int off = 128; off > 0; off >>= 1) {
        if (threadIdx.x < off) s[threadIdx.x] += s[threadIdx.x + off];
        __syncthreads();
    }
    if (threadIdx.x == 0) bsum[blockIdx.x] = s[0];
}

__global__ void scan_bsums_kernel(int* __restrict__ bsum, int* __restrict__ row_ptr) {
    __shared__ int s[512];
    int t = threadIdx.x;
    int v = (t < NB_SCAN) ? bsum[t] : 0;
    s[t] = v; __syncthreads();
    for (int off = 1; off < 512; off <<= 1) {
        int x = (t >= off) ? s[t - off] : 0;
        __syncthreads();
        s[t] += x;
        __syncthreads();
    }
    if (t < NB_SCAN) bsum[t] = s[t] - v;              // exclusive
    if (t == NB_SCAN - 1) row_ptr[N_NODES] = s[t];    // total (= N_EDGES)
}

// also zeroes counts so it can be reused as the scatter fill array
__global__ void write_rowptr_kernel(int* __restrict__ counts, const int* __restrict__ bsum,
                                    int* __restrict__ row_ptr) {
    __shared__ int s[256];
    int i = blockIdx.x * 256 + threadIdx.x;
    int v = (i < N_NODES) ? counts[i] : 0;
    s[threadIdx.x] = v; __syncthreads();
    for (int off = 1; off < 256; off <<= 1) {
        int x = (threadIdx.x >= off) ? s[threadIdx.x - off] : 0;
        __syncthreads();
        s[threadIdx.x] += x;
        __syncthreads();
    }
    if (i < N_NODES) {
        row_ptr[i] = bsum[blockIdx.x] + s[threadIdx.x] - v;  // exclusive
        counts[i] = 0;                                       // becomes fill[]
    }
}

__global__ void scatter_kernel(const int* __restrict__ rows, const int* __restrict__ cols,
                               const float* __restrict__ w, const int* __restrict__ row_ptr,
                               int* __restrict__ fill, int* __restrict__ cols_s,
                               float* __restrict__ w_s) {
    int e = blockIdx.x * blockDim.x + threadIdx.x;
    if (e < N_EDGES) {
        int r = rows[e];
        r = min(max(r, 0), N_NODES - 1);
        int pos = row_ptr[r] + atomicAdd(&fill[r], 1);
        pos = min(max(pos, 0), N_EDGES - 1);
        cols_s[pos] = cols[e];
        w_s[pos] = w[e];
    }
}

// -------- weight prep: W' = [W0-W2 | W1 | 2*W2], f32 -> bf16 ----------

__global__ void prep_w_kernel(const float* __restrict__ W, u16* __restrict__ Wp, int O) {
    int i = blockIdx.x * blockDim.x + threadIdx.x;
    if (i >= O * 384) return;
    int o = i / 384, k = i % 384;
    float v;
    if (k < 128)      v = W[o * 384 + k] - W[o * 384 + 256 + k];
    else if (k < 256) v = W[o * 384 + k];
    else              v = 2.0f * W[o * 384 + k];
    Wp[i] = f2bf(v);
}

// -------- SpMM: Y[r,:] = sum_e w_e * X[col_e,:]  (one wave per row) -----
// X is f32 (layer 1, gathers raw input x) or bf16 (later layers). Y is bf16.

template <bool IN_F32>
__global__ __launch_bounds__(256) void spmm_kernel(const int* __restrict__ row_ptr,
                                                   const int* __restrict__ cols,
                                                   const float* __restrict__ w,
                                                   const void* __restrict__ Xv,
                                                   u16* __restrict__ Y) {
    int wave = (blockIdx.x * blockDim.x + threadIdx.x) >> 6;
    int lane = threadIdx.x & 63;
    if (wave >= N_NODES) return;
    int s = row_ptr[wave], e = row_ptr[wave + 1];
    s = min(max(s, 0), N_EDGES); e = min(max(e, s), N_EDGES);
    float a0 = 0.f, a1 = 0.f;
    for (int b = s; b < e; b += 64) {
        int idx = b + lane;
        int c = 0; float wv = 0.f;
        if (idx < e) { c = cols[idx]; wv = w[idx]; }
        c = min(max(c, 0), N_NODES - 1);
        int cnt = min(64, e - b);
        for (int j = 0; j < cnt; ++j) {
            int cj = __shfl(c, j);
            float wj = __shfl(wv, j);
            if (IN_F32) {
                const float* X = (const float*)Xv;
                float2 pv = *(const float2*)(X + (size_t)cj * FEAT + lane * 2);
                a0 += wj * pv.x;
                a1 += wj * pv.y;
            } else {
                const u16* X = (const u16*)Xv;
                unsigned int pv = *(const unsigned int*)(X + (size_t)cj * FEAT + lane * 2);
                a0 += wj * bf2f((u16)(pv & 0xffffu));
                a1 += wj * bf2f((u16)(pv >> 16));
            }
        }
    }
    unsigned int outp = ((unsigned int)f2bf(a1) << 16) | (unsigned int)f2bf(a0);
    *(unsigned int*)(Y + (size_t)wave * FEAT + lane * 2) = outp;
}

// ------- fused: per 16-row tile, compute s2 tile (gather from bf16 T1) in LDS,
//         then out = act( H@W0' + T1@W1' + s2@W2' + b [+H] ) via MFMA.
//         H is f32 (layer 1: raw x) or bf16. out is bf16 (h) or f32 (d_out).
//         One wave per block so __syncthreads is trivially safe.

template <int O, bool RELU, bool RES, bool A_F32, bool OUT_F32>
__global__ __launch_bounds__(64) void fused_gemm_kernel(const int* __restrict__ row_ptr,
                                                        const int* __restrict__ cols,
                                                        const float* __restrict__ w,
                                                        const void* __restrict__ Hv,
                                                        const u16* __restrict__ T1,
                                                        const u16* __restrict__ Wp,
                                                        const float* __restrict__ bias,
                                                        void* __restrict__ outv) {
    __shared__ __align__(16) u16 sT[16 * FEAT];    // 4 KB: this tile's s2 rows
    int lane = threadIdx.x;
    int m0 = blockIdx.x * 16;

    // Phase 1: s2 rows for this tile, gathered from global bf16 T1
    for (int y = 0; y < 16; ++y) {
        int rr = m0 + y;
        int s = row_ptr[rr], e = row_ptr[rr + 1];
        s = min(max(s, 0), N_EDGES); e = min(max(e, s), N_EDGES);
        float a0 = 0.f, a1 = 0.f;
        for (int b = s; b < e; b += 64) {
            int idx = b + lane;
            int c = 0; float wv = 0.f;
            if (idx < e) { c = cols[idx]; wv = w[idx]; }
            c = min(max(c, 0), N_NODES - 1);
            int cnt = min(64, e - b);
            for (int j = 0; j < cnt; ++j) {
                int cj = __shfl(c, j);
                float wj = __shfl(wv, j);
                unsigned int pv = *(const unsigned int*)(T1 + (size_t)cj * FEAT + lane * 2);
                a0 += wj * bf2f((u16)(pv & 0xffffu));
                a1 += wj * bf2f((u16)(pv >> 16));
            }
        }
        *(unsigned int*)(sT + y * FEAT + lane * 2) =
            ((unsigned int)f2bf(a1) << 16) | (unsigned int)f2bf(a0);
    }
    __syncthreads();

    // Phase 2: MFMA over K = [H(128) | T1(128) | s2(128)]
    int r = lane & 15, q = lane >> 4;
    constexpr int NT = O / 16;
    f32x4 acc[NT];
#pragma unroll
    for (int t = 0; t < NT; ++t) acc[t] = (f32x4){0.f, 0.f, 0.f, 0.f};

#pragma unroll
    for (int kk = 0; kk < 12; ++kk) {
        bf16x8 af;
        if (kk < 4) {
            if (A_F32) {
                const float* H = (const float*)Hv;
                const float* p = H + (size_t)(m0 + r) * FEAT + (kk & 3) * 32 + q * 8;
                u16 tmp[8];
#pragma unroll
                for (int j = 0; j < 8; ++j) tmp[j] = f2bf(p[j]);
                af = *(const bf16x8*)tmp;
            } else {
                const u16* H = (const u16*)Hv;
                af = *(const bf16x8*)(H + (size_t)(m0 + r) * FEAT + (kk & 3) * 32 + q * 8);
            }
        } else if (kk < 8) {
            af = *(const bf16x8*)(T1 + (size_t)(m0 + r) * FEAT + (kk & 3) * 32 + q * 8);
        } else {
            af = *(const bf16x8*)(sT + r * FEAT + (kk - 8) * 32 + q * 8);
        }
#pragma unroll
        for (int t = 0; t < NT; ++t) {
            bf16x8 bfr = *(const bf16x8*)(Wp + (size_t)(t * 16 + r) * 384 + kk * 32 + q * 8);
            acc[t] = __builtin_amdgcn_mfma_f32_16x16x32_bf16(af, bfr, acc[t], 0, 0, 0);
        }
    }

#pragma unroll
    for (int t = 0; t < NT; ++t) {
        int col = t * 16 + r;
        float bv = bias[col];
#pragma unroll
        for (int i = 0; i < 4; ++i) {
            int row = m0 + q * 4 + i;
            float v = acc[t][i] + bv;
            if (RES) v += bf2f(((const u16*)Hv)[(size_t)row * FEAT + col]);  // RES only when H is bf16
            if (RELU) v = fmaxf(v, 0.f);
            if (OUT_F32) ((float*)outv)[(size_t)row * O + col] = v;
            else         ((u16*)outv)[(size_t)row * O + col] = f2bf(v);
        }
    }
}

// ---------------- launcher ----------------

static inline size_t align_up(size_t x) { return (x + 255) & ~(size_t)255; }

extern "C" void kernel_launch(void* const* d_in, const int* in_sizes, int n_in,
                              void* d_out, int out_size, void* d_ws, size_t ws_size,
                              hipStream_t stream) {
    const float* x     = (const float*)d_in[0];
    const int*   ei    = (const int*)d_in[1];
    const float* ew    = (const float*)d_in[2];
    const float* W_in  = (const float*)d_in[3];
    const float* b_in  = (const float*)d_in[4];
    const float* W_h1  = (const float*)d_in[5];
    const float* b_h1  = (const float*)d_in[6];
    const float* W_h2  = (const float*)d_in[7];
    const float* b_h2  = (const float*)d_in[8];
    const float* W_out = (const float*)d_in[9];
    const float* b_out = (const float*)d_in[10];

    const int* rows = ei;
    const int* cols = ei + N_EDGES;

    // workspace layout — ~62.1 MiB total
    char* w = (char*)d_ws;
    size_t off = 0;
    int* counts = (int*)(w + off);            off = align_up(off + (size_t)N_NODES * 4);   // reused as fill
    int* row_ptr= (int*)(w + off);            off = align_up(off + (size_t)(N_NODES + 1) * 4);
    int* bsum   = (int*)(w + off);            off = align_up(off + 512 * 4);
    int* cols_s = (int*)(w + off);            off = align_up(off + (size_t)N_EDGES * 4);
    float* w_s  = (float*)(w + off);          off = align_up(off + (size_t)N_EDGES * 4);
    u16* t1     = (u16*)(w + off);            off = align_up(off + (size_t)N_NODES * FEAT * 2);
    u16* h      = (u16*)(w + off);            off = align_up(off + (size_t)N_NODES * FEAT * 2);
    u16* Wp_in  = (u16*)(w + off);            off = align_up(off + (size_t)128 * 384 * 2);
    u16* Wp_h1  = (u16*)(w + off);            off = align_up(off + (size_t)128 * 384 * 2);
    u16* Wp_h2  = (u16*)(w + off);            off = align_up(off + (size_t)128 * 384 * 2);
    u16* Wp_out = (u16*)(w + off);            off = align_up(off + (size_t)64 * 384 * 2);

    hipMemsetAsync(counts, 0, (size_t)N_NODES * 4, stream);

    // weight prep (f32 -> bf16, Chebyshev recombination folded in)
    prep_w_kernel<<<(128 * 384 + 255) / 256, 256, 0, stream>>>(W_in, Wp_in, 128);
    prep_w_kernel<<<(128 * 384 + 255) / 256, 256, 0, stream>>>(W_h1, Wp_h1, 128);
    prep_w_kernel<<<(128 * 384 + 255) / 256, 256, 0, stream>>>(W_h2, Wp_h2, 128);
    prep_w_kernel<<<(64 * 384 + 255) / 256, 256, 0, stream>>>(W_out, Wp_out, 64);

    // CSR build (counting sort)
    hist_kernel<<<N_EDGES / 256, 256, 0, stream>>>(rows, counts);
    reduce_counts_kernel<<<NB_SCAN, 256, 0, stream>>>(counts, bsum);
    scan_bsums_kernel<<<1, 512, 0, stream>>>(bsum, row_ptr);
    write_rowptr_kernel<<<NB_SCAN, 256, 0, stream>>>(counts, bsum, row_ptr);  // zeroes counts -> fill
    scatter_kernel<<<N_EDGES / 256, 256, 0, stream>>>(rows, cols, ew, row_ptr, counts, cols_s, w_s);

    const int spmm_grid  = (N_NODES + 3) / 4;   // 4 rows (waves) per 256-thread block
    const int fused_grid = N_NODES / 16;        // 6250 single-wave blocks

    // Layer 1: h = relu(cheb(x))          (x f32; A-fragments converted on the fly)
    spmm_kernel<true><<<spmm_grid, 256, 0, stream>>>(row_ptr, cols_s, w_s, x, t1);
    fused_gemm_kernel<128, true, false, true, false><<<fused_grid, 64, 0, stream>>>(
        row_ptr, cols_s, w_s, x, t1, Wp_in, b_in, h);

    // Layer 2: h = relu(cheb(h) + h)
    spmm_kernel<false><<<spmm_grid, 256, 0, stream>>>(row_ptr, cols_s, w_s, h, t1);
    fused_gemm_kernel<128, true, true, false, false><<<fused_grid, 64, 0, stream>>>(
        row_ptr, cols_s, w_s, h, t1, Wp_h1, b_h1, h);

    // Layer 3: h = relu(cheb(h) + h)
    spmm_kernel<false><<<spmm_grid, 256, 0, stream>>>(row_ptr, cols_s, w_s, h, t1);
    fused_gemm_kernel<128, true, true, false, false><<<fused_grid, 64, 0, stream>>>(
        row_ptr, cols_s, w_s, h, t1, Wp_h2, b_h2, h);

    // Layer 4: out = cheb(h)   (O = 64, f32 output, no relu/residual)
    spmm_kernel<false><<<spmm_grid, 256, 0, stream>>>(row_ptr, cols_s, w_s, h, t1);
    fused_gemm_kernel<64, false, false, false, true><<<fused_grid, 64, 0, stream>>>(
        row_ptr, cols_s, w_s, h, t1, Wp_out, b_out, d_out);
}

// Round 4
// 1183.069 us; speedup vs baseline: 1.4835x; 1.4835x over previous
//
#include <hip/hip_runtime.h>
#include <hip/hip_bf16.h>
#include <stdint.h>
#include <stddef.h>

#define N_NODES 100000
#define N_EDGES 1600000
#define FEAT 128
#define NB_SCAN ((N_NODES + 255) / 256)   // 391 blocks of 256 for the scan
#define LDS_PITCH 144                     // 128 + 16 u16 pad (breaks 256B bank stride)

typedef __attribute__((ext_vector_type(8))) short bf16x8;
typedef __attribute__((ext_vector_type(4))) float f32x4;
typedef unsigned short u16;

__device__ __forceinline__ float bf2f(u16 u) {
    union { unsigned int i; float f; } v; v.i = ((unsigned int)u) << 16; return v.f;
}
__device__ __forceinline__ u16 f2bf(float f) {
    union { float f; unsigned int i; } v; v.f = f;
    unsigned int x = v.i;
    return (u16)((x + 0x7fffu + ((x >> 16) & 1u)) >> 16);   // round-nearest-even
}

// ---------------- CSR build ----------------

__global__ void hist_kernel(const int* __restrict__ rows, int* __restrict__ counts) {
    int e = blockIdx.x * blockDim.x + threadIdx.x;
    if (e < N_EDGES) {
        int r = rows[e];
        r = min(max(r, 0), N_NODES - 1);
        atomicAdd(&counts[r], 1);
    }
}

__global__ void reduce_counts_kernel(const int* __restrict__ counts, int* __restrict__ bsum) {
    __shared__ int s[256];
    int i = blockIdx.x * 256 + threadIdx.x;
    int v = (i < N_NODES) ? counts[i] : 0;
    s[threadIdx.x] = v; __syncthreads();
    for (int off = 128; off > 0; off >>= 1) {
        if (threadIdx.x < off) s[threadIdx.x] += s[threadIdx.x + off];
        __syncthreads();
    }
    if (threadIdx.x == 0) bsum[blockIdx.x] = s[0];
}

__global__ void scan_bsums_kernel(int* __restrict__ bsum, int* __restrict__ row_ptr) {
    __shared__ int s[512];
    int t = threadIdx.x;
    int v = (t < NB_SCAN) ? bsum[t] : 0;
    s[t] = v; __syncthreads();
    for (int off = 1; off < 512; off <<= 1) {
        int x = (t >= off) ? s[t - off] : 0;
        __syncthreads();
        s[t] += x;
        __syncthreads();
    }
    if (t < NB_SCAN) bsum[t] = s[t] - v;              // exclusive
    if (t == NB_SCAN - 1) row_ptr[N_NODES] = s[t];    // total (= N_EDGES)
}

// also zeroes counts so it can be reused as the scatter fill array
__global__ void write_rowptr_kernel(int* __restrict__ counts, const int* __restrict__ bsum,
                                    int* __restrict__ row_ptr) {
    __shared__ int s[256];
    int i = blockIdx.x * 256 + threadIdx.x;
    int v = (i < N_NODES) ? counts[i] : 0;
    s[threadIdx.x] = v; __syncthreads();
    for (int off = 1; off < 256; off <<= 1) {
        int x = (threadIdx.x >= off) ? s[threadIdx.x - off] : 0;
        __syncthreads();
        s[threadIdx.x] += x;
        __syncthreads();
    }
    if (i < N_NODES) {
        row_ptr[i] = bsum[blockIdx.x] + s[threadIdx.x] - v;  // exclusive
        counts[i] = 0;                                       // becomes fill[]
    }
}

// pack (col, weight-bits) per sorted edge slot
__global__ void scatter_kernel(const int* __restrict__ rows, const int* __restrict__ cols,
                               const float* __restrict__ w, const int* __restrict__ row_ptr,
                               int* __restrict__ fill, int2* __restrict__ ecw) {
    int e = blockIdx.x * blockDim.x + threadIdx.x;
    if (e < N_EDGES) {
        int r = rows[e];
        r = min(max(r, 0), N_NODES - 1);
        int pos = row_ptr[r] + atomicAdd(&fill[r], 1);
        pos = min(max(pos, 0), N_EDGES - 1);
        int c = cols[e];
        c = min(max(c, 0), N_NODES - 1);
        ecw[pos] = make_int2(c, __float_as_int(w[e]));
    }
}

// -------- weight prep: W' = [W0-W2 | W1 | 2*W2], f32 -> bf16 ----------

__global__ void prep_w_kernel(const float* __restrict__ W, u16* __restrict__ Wp, int O) {
    int i = blockIdx.x * blockDim.x + threadIdx.x;
    if (i >= O * 384) return;
    int o = i / 384, k = i % 384;
    float v;
    if (k < 128)      v = W[o * 384 + k] - W[o * 384 + 256 + k];
    else if (k < 256) v = W[o * 384 + k];
    else              v = 2.0f * W[o * 384 + k];
    Wp[i] = f2bf(v);
}

// -------- x (f32) -> bf16, 4 elems per thread ----------

__global__ void cvt_kernel(const float* __restrict__ x, u16* __restrict__ y) {
    int i = blockIdx.x * blockDim.x + threadIdx.x;
    if (i >= N_NODES * FEAT / 4) return;
    float4 v = ((const float4*)x)[i];
    ushort4 o;
    o.x = f2bf(v.x); o.y = f2bf(v.y); o.z = f2bf(v.z); o.w = f2bf(v.w);
    ((ushort4*)y)[i] = o;
}

// -------- edge-parallel gather core: one wave computes one output row ------
// lane = (g = edge slot 0..3, f = feature group 0..15), 16B load per lane,
// 4 edges in flight per iteration, main loop unrolled x2 (8 edges).
// Returns 8 f32 partials in acc[]; caller reduces over g (shfl_xor 16/32).

__device__ __forceinline__ void gather_row(const int2* __restrict__ ecw,
                                           const u16* __restrict__ X,
                                           int s, int e, int g, int f, float* acc) {
#pragma unroll 8
    for (int j = 0; j < 8; ++j) acc[j] = 0.f;
    int b = s;
    for (; b + 8 <= e; b += 8) {
        int2 cw0 = ecw[b + g];
        int2 cw1 = ecw[b + 4 + g];
        bf16x8 x0 = *(const bf16x8*)(X + (size_t)cw0.x * FEAT + f * 8);
        bf16x8 x1 = *(const bf16x8*)(X + (size_t)cw1.x * FEAT + f * 8);
        float w0 = __int_as_float(cw0.y);
        float w1 = __int_as_float(cw1.y);
#pragma unroll 8
        for (int j = 0; j < 8; ++j) acc[j] += w0 * bf2f((u16)x0[j]);
#pragma unroll 8
        for (int j = 0; j < 8; ++j) acc[j] += w1 * bf2f((u16)x1[j]);
    }
    for (; b < e; b += 4) {
        int idx = b + g;
        int2 cw = (idx < e) ? ecw[idx] : make_int2(0, 0);
        bf16x8 xv = *(const bf16x8*)(X + (size_t)cw.x * FEAT + f * 8);
        float wv = __int_as_float(cw.y);
#pragma unroll 8
        for (int j = 0; j < 8; ++j) acc[j] += wv * bf2f((u16)xv[j]);
    }
}

__device__ __forceinline__ void reduce_g(float* acc) {
#pragma unroll 8
    for (int j = 0; j < 8; ++j) {
        acc[j] += __shfl_xor(acc[j], 16);
        acc[j] += __shfl_xor(acc[j], 32);
    }
}

// -------- SpMM: Y[r,:] = sum_e w_e * X[col_e,:]  (one wave per row, bf16->bf16)

__global__ __launch_bounds__(256) void spmm_kernel(const int* __restrict__ row_ptr,
                                                   const int2* __restrict__ ecw,
                                                   const u16* __restrict__ X,
                                                   u16* __restrict__ Y) {
    int wave = (blockIdx.x * blockDim.x + threadIdx.x) >> 6;
    int lane = threadIdx.x & 63;
    if (wave >= N_NODES) return;
    int g = lane >> 4, f = lane & 15;
    int s = row_ptr[wave], e = row_ptr[wave + 1];
    float acc[8];
    gather_row(ecw, X, s, e, g, f, acc);
    reduce_g(acc);
    if (g == 0) {
        u16 tmp[8];
#pragma unroll 8
        for (int j = 0; j < 8; ++j) tmp[j] = f2bf(acc[j]);
        *(bf16x8*)(Y + (size_t)wave * FEAT + f * 8) = *(const bf16x8*)tmp;
    }
}

// ------- fused: 4 waves/block, wave w owns 16-row tile; gathers its s2 tile into
//         a private LDS section (no barrier needed), then
//         out = act( H@W0' + T1@W1' + s2@W2' + b [+H] ) via MFMA.

template <int O, bool RELU, bool RES, bool OUT_F32>
__global__ __launch_bounds__(256) void fused_gemm_kernel(const int* __restrict__ row_ptr,
                                                         const int2* __restrict__ ecw,
                                                         const u16* __restrict__ H,
                                                         const u16* __restrict__ T1,
                                                         const u16* __restrict__ Wp,
                                                         const float* __restrict__ bias,
                                                         void* __restrict__ outv) {
    __shared__ __align__(16) u16 sT[4 * 16 * LDS_PITCH];    // 18 KB
    int wid = threadIdx.x >> 6, lane = threadIdx.x & 63;
    int m0 = (blockIdx.x * 4 + wid) * 16;
    int g = lane >> 4, f = lane & 15;
    u16* myT = sT + wid * 16 * LDS_PITCH;

    // Phase 1: s2 rows for this wave's tile (gather from global bf16 T1)
    for (int y = 0; y < 16; ++y) {
        int rr = m0 + y;
        int s = 0, e = 0;
        if (rr < N_NODES) { s = row_ptr[rr]; e = row_ptr[rr + 1]; }
        float acc[8];
        gather_row(ecw, T1, s, e, g, f, acc);
        reduce_g(acc);
        if (g == 0) {
            u16 tmp[8];
#pragma unroll 8
            for (int j = 0; j < 8; ++j) tmp[j] = f2bf(acc[j]);
            *(bf16x8*)(myT + y * LDS_PITCH + f * 8) = *(const bf16x8*)tmp;
        }
    }
    // no __syncthreads: each wave reads only its own LDS section (lgkmcnt handles it)

    // Phase 2: MFMA over K = [H(128) | T1(128) | s2(128)]
    int r = f, q = g;
    int arow = min(m0 + r, N_NODES - 1);
    constexpr int NT = O / 16;
    f32x4 acc[NT];
#pragma unroll
    for (int t = 0; t < NT; ++t) acc[t] = (f32x4){0.f, 0.f, 0.f, 0.f};

#pragma unroll
    for (int kk = 0; kk < 12; ++kk) {
        bf16x8 af;
        if (kk < 4)
            af = *(const bf16x8*)(H + (size_t)arow * FEAT + kk * 32 + q * 8);
        else if (kk < 8)
            af = *(const bf16x8*)(T1 + (size_t)arow * FEAT + (kk - 4) * 32 + q * 8);
        else
            af = *(const bf16x8*)(myT + r * LDS_PITCH + (kk - 8) * 32 + q * 8);
#pragma unroll
        for (int t = 0; t < NT; ++t) {
            bf16x8 bfr = *(const bf16x8*)(Wp + (size_t)(t * 16 + r) * 384 + kk * 32 + q * 8);
            acc[t] = __builtin_amdgcn_mfma_f32_16x16x32_bf16(af, bfr, acc[t], 0, 0, 0);
        }
    }

#pragma unroll
    for (int t = 0; t < NT; ++t) {
        int col = t * 16 + r;
        float bv = bias[col];
#pragma unroll
        for (int i = 0; i < 4; ++i) {
            int row = m0 + q * 4 + i;
            if (row < N_NODES) {
                float v = acc[t][i] + bv;
                if (RES)  v += bf2f(H[(size_t)row * FEAT + col]);
                if (RELU) v = fmaxf(v, 0.f);
                if (OUT_F32) ((float*)outv)[(size_t)row * O + col] = v;
                else         ((u16*)outv)[(size_t)row * O + col] = f2bf(v);
            }
        }
    }
}

// ---------------- launcher ----------------

static inline size_t align_up(size_t x) { return (x + 255) & ~(size_t)255; }

extern "C" void kernel_launch(void* const* d_in, const int* in_sizes, int n_in,
                              void* d_out, int out_size, void* d_ws, size_t ws_size,
                              hipStream_t stream) {
    const float* x     = (const float*)d_in[0];
    const int*   ei    = (const int*)d_in[1];
    const float* ew    = (const float*)d_in[2];
    const float* W_in  = (const float*)d_in[3];
    const float* b_in  = (const float*)d_in[4];
    const float* W_h1  = (const float*)d_in[5];
    const float* b_h1  = (const float*)d_in[6];
    const float* W_h2  = (const float*)d_in[7];
    const float* b_h2  = (const float*)d_in[8];
    const float* W_out = (const float*)d_in[9];
    const float* b_out = (const float*)d_in[10];

    const int* rows = ei;
    const int* cols = ei + N_EDGES;

    // workspace layout — ~65.2 MB (same budget as the round-3 passing version)
    char* w = (char*)d_ws;
    size_t off = 0;
    int* counts = (int*)(w + off);            off = align_up(off + (size_t)N_NODES * 4);   // reused as fill
    int* row_ptr= (int*)(w + off);            off = align_up(off + (size_t)(N_NODES + 1) * 4);
    int* bsum   = (int*)(w + off);            off = align_up(off + 512 * 4);
    int2* ecw   = (int2*)(w + off);           off = align_up(off + (size_t)N_EDGES * 8);
    u16* t1     = (u16*)(w + off);            off = align_up(off + (size_t)N_NODES * FEAT * 2);
    u16* h      = (u16*)(w + off);            off = align_up(off + (size_t)N_NODES * FEAT * 2);
    u16* Wp_in  = (u16*)(w + off);            off = align_up(off + (size_t)128 * 384 * 2);
    u16* Wp_h1  = (u16*)(w + off);            off = align_up(off + (size_t)128 * 384 * 2);
    u16* Wp_h2  = (u16*)(w + off);            off = align_up(off + (size_t)128 * 384 * 2);
    u16* Wp_out = (u16*)(w + off);            off = align_up(off + (size_t)64 * 384 * 2);

    hipMemsetAsync(counts, 0, (size_t)N_NODES * 4, stream);

    // weight prep + input conversion
    prep_w_kernel<<<(128 * 384 + 255) / 256, 256, 0, stream>>>(W_in, Wp_in, 128);
    prep_w_kernel<<<(128 * 384 + 255) / 256, 256, 0, stream>>>(W_h1, Wp_h1, 128);
    prep_w_kernel<<<(128 * 384 + 255) / 256, 256, 0, stream>>>(W_h2, Wp_h2, 128);
    prep_w_kernel<<<(64 * 384 + 255) / 256, 256, 0, stream>>>(W_out, Wp_out, 64);
    cvt_kernel<<<(N_NODES * FEAT / 4 + 255) / 256, 256, 0, stream>>>(x, h);

    // CSR build (counting sort)
    hist_kernel<<<N_EDGES / 256, 256, 0, stream>>>(rows, counts);
    reduce_counts_kernel<<<NB_SCAN, 256, 0, stream>>>(counts, bsum);
    scan_bsums_kernel<<<1, 512, 0, stream>>>(bsum, row_ptr);
    write_rowptr_kernel<<<NB_SCAN, 256, 0, stream>>>(counts, bsum, row_ptr);  // zeroes counts -> fill
    scatter_kernel<<<N_EDGES / 256, 256, 0, stream>>>(rows, cols, ew, row_ptr, counts, ecw);

    const int spmm_grid  = (N_NODES + 3) / 4;   // 4 rows (waves) per 256-thread block
    const int fused_grid = (N_NODES / 16 + 3) / 4;   // 4 tiles per block

    // Layer 1: h = relu(cheb(x))    (x pre-converted to bf16 in h; in-place row-local GEMM)
    spmm_kernel<<<spmm_grid, 256, 0, stream>>>(row_ptr, ecw, h, t1);
    fused_gemm_kernel<128, true, false, false><<<fused_grid, 256, 0, stream>>>(
        row_ptr, ecw, h, t1, Wp_in, b_in, h);

    // Layer 2: h = relu(cheb(h) + h)
    spmm_kernel<<<spmm_grid, 256, 0, stream>>>(row_ptr, ecw, h, t1);
    fused_gemm_kernel<128, true, true, false><<<fused_grid, 256, 0, stream>>>(
        row_ptr, ecw, h, t1, Wp_h1, b_h1, h);

    // Layer 3: h = relu(cheb(h) + h)
    spmm_kernel<<<spmm_grid, 256, 0, stream>>>(row_ptr, ecw, h, t1);
    fused_gemm_kernel<128, true, true, false><<<fused_grid, 256, 0, stream>>>(
        row_ptr, ecw, h, t1, Wp_h2, b_h2, h);

    // Layer 4: out = cheb(h)   (O = 64, f32 output, no relu/residual)
    spmm_kernel<<<spmm_grid, 256, 0, stream>>>(row_ptr, ecw, h, t1);
    fused_gemm_kernel<64, false, false, true><<<fused_grid, 256, 0, stream>>>(
        row_ptr, ecw, h, t1, Wp_out, b_out, d_out);
}

// Round 5
// 1156.480 us; speedup vs baseline: 1.5176x; 1.0230x over previous
//
#include <hip/hip_runtime.h>
#include <hip/hip_bf16.h>
#include <stdint.h>
#include <stddef.h>

#define N_NODES 100000
#define N_EDGES 1600000
#define FEAT 128
#define NB_SCAN ((N_NODES + 255) / 256)   // 391 blocks of 256 for the scan
#define LDS_PITCH 136                     // u16; 272 B/row = 68 dw -> 2-way bank alias (free)

typedef __attribute__((ext_vector_type(8))) short bf16x8;
typedef __attribute__((ext_vector_type(4))) float f32x4;
typedef unsigned short u16;

__device__ __forceinline__ float bf2f(u16 u) {
    union { unsigned int i; float f; } v; v.i = ((unsigned int)u) << 16; return v.f;
}
__device__ __forceinline__ u16 f2bf(float f) {
    union { float f; unsigned int i; } v; v.f = f;
    unsigned int x = v.i;
    return (u16)((x + 0x7fffu + ((x >> 16) & 1u)) >> 16);   // round-nearest-even
}

// ---------------- CSR build ----------------

__global__ void hist_kernel(const int* __restrict__ rows, int* __restrict__ counts) {
    int e = blockIdx.x * blockDim.x + threadIdx.x;
    if (e < N_EDGES) {
        int r = rows[e];
        r = min(max(r, 0), N_NODES - 1);
        atomicAdd(&counts[r], 1);
    }
}

__global__ void reduce_counts_kernel(const int* __restrict__ counts, int* __restrict__ bsum) {
    __shared__ int s[256];
    int i = blockIdx.x * 256 + threadIdx.x;
    int v = (i < N_NODES) ? counts[i] : 0;
    s[threadIdx.x] = v; __syncthreads();
    for (int off = 128; off > 0; off >>= 1) {
        if (threadIdx.x < off) s[threadIdx.x] += s[threadIdx.x + off];
        __syncthreads();
    }
    if (threadIdx.x == 0) bsum[blockIdx.x] = s[0];
}

__global__ void scan_bsums_kernel(int* __restrict__ bsum, int* __restrict__ row_ptr) {
    __shared__ int s[512];
    int t = threadIdx.x;
    int v = (t < NB_SCAN) ? bsum[t] : 0;
    s[t] = v; __syncthreads();
    for (int off = 1; off < 512; off <<= 1) {
        int x = (t >= off) ? s[t - off] : 0;
        __syncthreads();
        s[t] += x;
        __syncthreads();
    }
    if (t < NB_SCAN) bsum[t] = s[t] - v;              // exclusive
    if (t == NB_SCAN - 1) row_ptr[N_NODES] = s[t];    // total (= N_EDGES)
}

// also zeroes counts so it can be reused as the scatter fill array
__global__ void write_rowptr_kernel(int* __restrict__ counts, const int* __restrict__ bsum,
                                    int* __restrict__ row_ptr) {
    __shared__ int s[256];
    int i = blockIdx.x * 256 + threadIdx.x;
    int v = (i < N_NODES) ? counts[i] : 0;
    s[threadIdx.x] = v; __syncthreads();
    for (int off = 1; off < 256; off <<= 1) {
        int x = (threadIdx.x >= off) ? s[threadIdx.x - off] : 0;
        __syncthreads();
        s[threadIdx.x] += x;
        __syncthreads();
    }
    if (i < N_NODES) {
        row_ptr[i] = bsum[blockIdx.x] + s[threadIdx.x] - v;  // exclusive
        counts[i] = 0;                                       // becomes fill[]
    }
}

// pack (col, weight-bits) per sorted edge slot
__global__ void scatter_kernel(const int* __restrict__ rows, const int* __restrict__ cols,
                               const float* __restrict__ w, const int* __restrict__ row_ptr,
                               int* __restrict__ fill, int2* __restrict__ ecw) {
    int e = blockIdx.x * blockDim.x + threadIdx.x;
    if (e < N_EDGES) {
        int r = rows[e];
        r = min(max(r, 0), N_NODES - 1);
        int pos = row_ptr[r] + atomicAdd(&fill[r], 1);
        pos = min(max(pos, 0), N_EDGES - 1);
        int c = cols[e];
        c = min(max(c, 0), N_NODES - 1);
        ecw[pos] = make_int2(c, __float_as_int(w[e]));
    }
}

// -------- weight prep: W' = [W0-W2 | W1 | 2*W2], f32 -> bf16 ----------

__global__ void prep_w_kernel(const float* __restrict__ W, u16* __restrict__ Wp, int O) {
    int i = blockIdx.x * blockDim.x + threadIdx.x;
    if (i >= O * 384) return;
    int o = i / 384, k = i % 384;
    float v;
    if (k < 128)      v = W[o * 384 + k] - W[o * 384 + 256 + k];
    else if (k < 256) v = W[o * 384 + k];
    else              v = 2.0f * W[o * 384 + k];
    Wp[i] = f2bf(v);
}

// -------- x (f32) -> bf16, 4 elems per thread ----------

__global__ void cvt_kernel(const float* __restrict__ x, u16* __restrict__ y) {
    int i = blockIdx.x * blockDim.x + threadIdx.x;
    if (i >= N_NODES * FEAT / 4) return;
    float4 v = ((const float4*)x)[i];
    ushort4 o;
    o.x = f2bf(v.x); o.y = f2bf(v.y); o.z = f2bf(v.z); o.w = f2bf(v.w);
    ((ushort4*)y)[i] = o;
}

// -------- edge-parallel gather core -----------------------------------------
// lane = (g = edge slot 0..7, f = feature group 0..7); each lane covers 16
// features via two 16B loads. Main loop: 16 edges/iter, 4 gathers + 2 meta
// loads in flight per lane. Caller reduces over g via shfl_xor(1,2,4).

__device__ __forceinline__ void gather_row16(const int2* __restrict__ ecw,
                                             const u16* __restrict__ X,
                                             int s, int e, int g, int f, float* acc) {
#pragma unroll
    for (int j = 0; j < 16; ++j) acc[j] = 0.f;
    int b = s;
    for (; b + 16 <= e; b += 16) {
        int2 cw0 = ecw[b + g];
        int2 cw1 = ecw[b + 8 + g];
        const u16* p0 = X + (size_t)cw0.x * FEAT + f * 16;
        const u16* p1 = X + (size_t)cw1.x * FEAT + f * 16;
        bf16x8 a0 = *(const bf16x8*)p0;
        bf16x8 a1 = *(const bf16x8*)(p0 + 8);
        bf16x8 b0 = *(const bf16x8*)p1;
        bf16x8 b1 = *(const bf16x8*)(p1 + 8);
        float w0 = __int_as_float(cw0.y);
        float w1 = __int_as_float(cw1.y);
#pragma unroll
        for (int j = 0; j < 8; ++j) acc[j]     += w0 * bf2f((u16)a0[j]);
#pragma unroll
        for (int j = 0; j < 8; ++j) acc[8 + j] += w0 * bf2f((u16)a1[j]);
#pragma unroll
        for (int j = 0; j < 8; ++j) acc[j]     += w1 * bf2f((u16)b0[j]);
#pragma unroll
        for (int j = 0; j < 8; ++j) acc[8 + j] += w1 * bf2f((u16)b1[j]);
    }
    for (; b < e; b += 8) {
        int idx = b + g;
        int2 cw = (idx < e) ? ecw[idx] : make_int2(0, 0);   // w=0 for pad lanes
        const u16* p = X + (size_t)cw.x * FEAT + f * 16;
        bf16x8 a0 = *(const bf16x8*)p;
        bf16x8 a1 = *(const bf16x8*)(p + 8);
        float wv = __int_as_float(cw.y);
#pragma unroll
        for (int j = 0; j < 8; ++j) acc[j]     += wv * bf2f((u16)a0[j]);
#pragma unroll
        for (int j = 0; j < 8; ++j) acc[8 + j] += wv * bf2f((u16)a1[j]);
    }
}

__device__ __forceinline__ void reduce_g8(float* acc) {
#pragma unroll
    for (int j = 0; j < 16; ++j) {
        acc[j] += __shfl_xor(acc[j], 1);
        acc[j] += __shfl_xor(acc[j], 2);
        acc[j] += __shfl_xor(acc[j], 4);
    }
}

// -------- SpMM: Y[r,:] = sum_e w_e * X[col_e,:]  (one wave per row, bf16->bf16)

__global__ __launch_bounds__(256) void spmm_kernel(const int* __restrict__ row_ptr,
                                                   const int2* __restrict__ ecw,
                                                   const u16* __restrict__ X,
                                                   u16* __restrict__ Y) {
    int wave = (blockIdx.x * blockDim.x + threadIdx.x) >> 6;
    int lane = threadIdx.x & 63;
    if (wave >= N_NODES) return;
    int g = lane & 7, f = lane >> 3;
    int s = row_ptr[wave], e = row_ptr[wave + 1];
    float acc[16];
    gather_row16(ecw, X, s, e, g, f, acc);
    reduce_g8(acc);
    if (g == 0) {
        u16 tmp[16];
#pragma unroll
        for (int j = 0; j < 16; ++j) tmp[j] = f2bf(acc[j]);
        u16* dst = Y + (size_t)wave * FEAT + f * 16;
        *(bf16x8*)dst = *(const bf16x8*)tmp;
        *(bf16x8*)(dst + 8) = *(const bf16x8*)(tmp + 8);
    }
}

// ------- fused: one block = one 16-row tile. Phase 1: the 4 waves gather 4 s2
//         rows each into the shared LDS tile (full row-parallelism). Phase 2:
//         each wave computes O/64 column-tiles of
//         out = act( H@W0' + T1@W1' + s2@W2' + b [+H] ) via MFMA.

template <int O, bool RELU, bool RES, bool OUT_F32>
__global__ __launch_bounds__(256) void fused_gemm_kernel(const int* __restrict__ row_ptr,
                                                         const int2* __restrict__ ecw,
                                                         const u16* __restrict__ H,
                                                         const u16* __restrict__ T1,
                                                         const u16* __restrict__ Wp,
                                                         const float* __restrict__ bias,
                                                         void* __restrict__ outv) {
    __shared__ __align__(16) u16 sT[16 * LDS_PITCH];    // 4.25 KB: the tile's s2 rows
    int wid = threadIdx.x >> 6, lane = threadIdx.x & 63;
    int m0 = blockIdx.x * 16;                            // N_NODES % 16 == 0
    int g = lane & 7, f = lane >> 3;

    // Phase 1: wave wid gathers rows y = wid*4 .. wid*4+3
#pragma unroll
    for (int y = wid * 4; y < wid * 4 + 4; ++y) {
        int rr = m0 + y;
        int s = row_ptr[rr], e = row_ptr[rr + 1];
        float acc[16];
        gather_row16(ecw, T1, s, e, g, f, acc);
        reduce_g8(acc);
        if (g == 0) {
            u16 tmp[16];
#pragma unroll
            for (int j = 0; j < 16; ++j) tmp[j] = f2bf(acc[j]);
            u16* dst = sT + y * LDS_PITCH + f * 16;
            *(bf16x8*)dst = *(const bf16x8*)tmp;
            *(bf16x8*)(dst + 8) = *(const bf16x8*)(tmp + 8);
        }
    }
    __syncthreads();

    // Phase 2: MFMA over K = [H(128) | T1(128) | s2(128)], wave wid owns
    // column-tiles t = wid*NW .. wid*NW+NW-1
    int r = lane & 15, q = lane >> 4;
    constexpr int NT = O / 16;
    constexpr int NW = NT / 4;          // 2 for O=128, 1 for O=64
    f32x4 acc[NW];
#pragma unroll
    for (int t = 0; t < NW; ++t) acc[t] = (f32x4){0.f, 0.f, 0.f, 0.f};

#pragma unroll
    for (int kk = 0; kk < 12; ++kk) {
        bf16x8 af;
        if (kk < 4)
            af = *(const bf16x8*)(H + (size_t)(m0 + r) * FEAT + kk * 32 + q * 8);
        else if (kk < 8)
            af = *(const bf16x8*)(T1 + (size_t)(m0 + r) * FEAT + (kk - 4) * 32 + q * 8);
        else
            af = *(const bf16x8*)(sT + r * LDS_PITCH + (kk - 8) * 32 + q * 8);
#pragma unroll
        for (int t = 0; t < NW; ++t) {
            int ot = wid * NW + t;
            bf16x8 bfr = *(const bf16x8*)(Wp + (size_t)(ot * 16 + r) * 384 + kk * 32 + q * 8);
            acc[t] = __builtin_amdgcn_mfma_f32_16x16x32_bf16(af, bfr, acc[t], 0, 0, 0);
        }
    }

#pragma unroll
    for (int t = 0; t < NW; ++t) {
        int col = (wid * NW + t) * 16 + r;
        float bv = bias[col];
#pragma unroll
        for (int i = 0; i < 4; ++i) {
            int row = m0 + q * 4 + i;
            float v = acc[t][i] + bv;
            if (RES)  v += bf2f(H[(size_t)row * FEAT + col]);
            if (RELU) v = fmaxf(v, 0.f);
            if (OUT_F32) ((float*)outv)[(size_t)row * O + col] = v;
            else         ((u16*)outv)[(size_t)row * O + col] = f2bf(v);
        }
    }
}

// ---------------- launcher ----------------

static inline size_t align_up(size_t x) { return (x + 255) & ~(size_t)255; }

extern "C" void kernel_launch(void* const* d_in, const int* in_sizes, int n_in,
                              void* d_out, int out_size, void* d_ws, size_t ws_size,
                              hipStream_t stream) {
    const float* x     = (const float*)d_in[0];
    const int*   ei    = (const int*)d_in[1];
    const float* ew    = (const float*)d_in[2];
    const float* W_in  = (const float*)d_in[3];
    const float* b_in  = (const float*)d_in[4];
    const float* W_h1  = (const float*)d_in[5];
    const float* b_h1  = (const float*)d_in[6];
    const float* W_h2  = (const float*)d_in[7];
    const float* b_h2  = (const float*)d_in[8];
    const float* W_out = (const float*)d_in[9];
    const float* b_out = (const float*)d_in[10];

    const int* rows = ei;
    const int* cols = ei + N_EDGES;

    // workspace layout — ~65.2 MB (proven budget)
    char* w = (char*)d_ws;
    size_t off = 0;
    int* counts = (int*)(w + off);            off = align_up(off + (size_t)N_NODES * 4);   // reused as fill
    int* row_ptr= (int*)(w + off);            off = align_up(off + (size_t)(N_NODES + 1) * 4);
    int* bsum   = (int*)(w + off);            off = align_up(off + 512 * 4);
    int2* ecw   = (int2*)(w + off);           off = align_up(off + (size_t)N_EDGES * 8);
    u16* t1     = (u16*)(w + off);            off = align_up(off + (size_t)N_NODES * FEAT * 2);
    u16* h      = (u16*)(w + off);            off = align_up(off + (size_t)N_NODES * FEAT * 2);
    u16* Wp_in  = (u16*)(w + off);            off = align_up(off + (size_t)128 * 384 * 2);
    u16* Wp_h1  = (u16*)(w + off);            off = align_up(off + (size_t)128 * 384 * 2);
    u16* Wp_h2  = (u16*)(w + off);            off = align_up(off + (size_t)128 * 384 * 2);
    u16* Wp_out = (u16*)(w + off);            off = align_up(off + (size_t)64 * 384 * 2);

    hipMemsetAsync(counts, 0, (size_t)N_NODES * 4, stream);

    // weight prep + input conversion
    prep_w_kernel<<<(128 * 384 + 255) / 256, 256, 0, stream>>>(W_in, Wp_in, 128);
    prep_w_kernel<<<(128 * 384 + 255) / 256, 256, 0, stream>>>(W_h1, Wp_h1, 128);
    prep_w_kernel<<<(128 * 384 + 255) / 256, 256, 0, stream>>>(W_h2, Wp_h2, 128);
    prep_w_kernel<<<(64 * 384 + 255) / 256, 256, 0, stream>>>(W_out, Wp_out, 64);
    cvt_kernel<<<(N_NODES * FEAT / 4 + 255) / 256, 256, 0, stream>>>(x, h);

    // CSR build (counting sort)
    hist_kernel<<<N_EDGES / 256, 256, 0, stream>>>(rows, counts);
    reduce_counts_kernel<<<NB_SCAN, 256, 0, stream>>>(counts, bsum);
    scan_bsums_kernel<<<1, 512, 0, stream>>>(bsum, row_ptr);
    write_rowptr_kernel<<<NB_SCAN, 256, 0, stream>>>(counts, bsum, row_ptr);  // zeroes counts -> fill
    scatter_kernel<<<N_EDGES / 256, 256, 0, stream>>>(rows, cols, ew, row_ptr, counts, ecw);

    const int spmm_grid  = N_NODES / 4;    // 4 rows (waves) per 256-thread block
    const int fused_grid = N_NODES / 16;   // one 16-row tile per block, 4 waves cooperate

    // Layer 1: h = relu(cheb(x))    (x pre-converted to bf16 in h; in-place row-local GEMM)
    spmm_kernel<<<spmm_grid, 256, 0, stream>>>(row_ptr, ecw, h, t1);
    fused_gemm_kernel<128, true, false, false><<<fused_grid, 256, 0, stream>>>(
        row_ptr, ecw, h, t1, Wp_in, b_in, h);

    // Layer 2: h = relu(cheb(h) + h)
    spmm_kernel<<<spmm_grid, 256, 0, stream>>>(row_ptr, ecw, h, t1);
    fused_gemm_kernel<128, true, true, false><<<fused_grid, 256, 0, stream>>>(
        row_ptr, ecw, h, t1, Wp_h1, b_h1, h);

    // Layer 3: h = relu(cheb(h) + h)
    spmm_kernel<<<spmm_grid, 256, 0, stream>>>(row_ptr, ecw, h, t1);
    fused_gemm_kernel<128, true, true, false><<<fused_grid, 256, 0, stream>>>(
        row_ptr, ecw, h, t1, Wp_h2, b_h2, h);

    // Layer 4: out = cheb(h)   (O = 64, f32 output, no relu/residual)
    spmm_kernel<<<spmm_grid, 256, 0, stream>>>(row_ptr, ecw, h, t1);
    fused_gemm_kernel<64, false, false, true><<<fused_grid, 256, 0, stream>>>(
        row_ptr, ecw, h, t1, Wp_out, b_out, d_out);
}

// Round 6
// 1047.301 us; speedup vs baseline: 1.6759x; 1.1042x over previous
//
#include <hip/hip_runtime.h>
#include <hip/hip_bf16.h>
#include <stdint.h>
#include <stddef.h>

#define N_NODES 100000
#define N_EDGES 1600000
#define FEAT 128
#define NB_SCAN ((N_NODES + 255) / 256)   // 391 blocks of 256 for the scan
#define LDS_PITCH 136                     // u16; 272 B/row = 2-way bank alias (free)
#define CAP 24                            // edges staged per chunk (24*256B = 6 KB/wave)

typedef __attribute__((ext_vector_type(8))) short bf16x8;
typedef __attribute__((ext_vector_type(4))) float f32x4;
typedef unsigned short u16;

typedef __attribute__((address_space(1))) void g_void;
typedef __attribute__((address_space(3))) void s_void;

// async gather: 64 lanes x 16B -> contiguous 1KB of LDS (4 edge rows of 256B).
// lds base must be wave-uniform; lane i deposits at base + i*16.
__device__ __forceinline__ void dma16(const void* g, const void* l) {
    __builtin_amdgcn_global_load_lds((g_void*)(uintptr_t)g,
                                     (s_void*)(uint32_t)(uintptr_t)l, 16, 0, 0);
}

__device__ __forceinline__ float bf2f(u16 u) {
    union { unsigned int i; float f; } v; v.i = ((unsigned int)u) << 16; return v.f;
}
__device__ __forceinline__ u16 f2bf(float f) {
    union { float f; unsigned int i; } v; v.f = f;
    unsigned int x = v.i;
    return (u16)((x + 0x7fffu + ((x >> 16) & 1u)) >> 16);   // round-nearest-even
}

// ---------------- CSR build ----------------

__global__ void hist_kernel(const int* __restrict__ rows, int* __restrict__ counts) {
    int e = blockIdx.x * blockDim.x + threadIdx.x;
    if (e < N_EDGES) {
        int r = rows[e];
        r = min(max(r, 0), N_NODES - 1);
        atomicAdd(&counts[r], 1);
    }
}

__global__ void reduce_counts_kernel(const int* __restrict__ counts, int* __restrict__ bsum) {
    __shared__ int s[256];
    int i = blockIdx.x * 256 + threadIdx.x;
    int v = (i < N_NODES) ? counts[i] : 0;
    s[threadIdx.x] = v; __syncthreads();
    for (int off = 128; off > 0; off >>= 1) {
        if (threadIdx.x < off) s[threadIdx.x] += s[threadIdx.x + off];
        __syncthreads();
    }
    if (threadIdx.x == 0) bsum[blockIdx.x] = s[0];
}

__global__ void scan_bsums_kernel(int* __restrict__ bsum, int* __restrict__ row_ptr) {
    __shared__ int s[512];
    int t = threadIdx.x;
    int v = (t < NB_SCAN) ? bsum[t] : 0;
    s[t] = v; __syncthreads();
    for (int off = 1; off < 512; off <<= 1) {
        int x = (t >= off) ? s[t - off] : 0;
        __syncthreads();
        s[t] += x;
        __syncthreads();
    }
    if (t < NB_SCAN) bsum[t] = s[t] - v;              // exclusive
    if (t == NB_SCAN - 1) row_ptr[N_NODES] = s[t];    // total (= N_EDGES)
}

// also zeroes counts so it can be reused as the scatter fill array
__global__ void write_rowptr_kernel(int* __restrict__ counts, const int* __restrict__ bsum,
                                    int* __restrict__ row_ptr) {
    __shared__ int s[256];
    int i = blockIdx.x * 256 + threadIdx.x;
    int v = (i < N_NODES) ? counts[i] : 0;
    s[threadIdx.x] = v; __syncthreads();
    for (int off = 1; off < 256; off <<= 1) {
        int x = (threadIdx.x >= off) ? s[threadIdx.x - off] : 0;
        __syncthreads();
        s[threadIdx.x] += x;
        __syncthreads();
    }
    if (i < N_NODES) {
        row_ptr[i] = bsum[blockIdx.x] + s[threadIdx.x] - v;  // exclusive
        counts[i] = 0;                                       // becomes fill[]
    }
}

// pack (col, weight-bits) per sorted edge slot
__global__ void scatter_kernel(const int* __restrict__ rows, const int* __restrict__ cols,
                               const float* __restrict__ w, const int* __restrict__ row_ptr,
                               int* __restrict__ fill, int2* __restrict__ ecw) {
    int e = blockIdx.x * blockDim.x + threadIdx.x;
    if (e < N_EDGES) {
        int r = rows[e];
        r = min(max(r, 0), N_NODES - 1);
        int pos = row_ptr[r] + atomicAdd(&fill[r], 1);
        pos = min(max(pos, 0), N_EDGES - 1);
        int c = cols[e];
        c = min(max(c, 0), N_NODES - 1);
        ecw[pos] = make_int2(c, __float_as_int(w[e]));
    }
}

// -------- weight prep: W' = [W0-W2 | W1 | 2*W2], f32 -> bf16 ----------

__global__ void prep_w_kernel(const float* __restrict__ W, u16* __restrict__ Wp, int O) {
    int i = blockIdx.x * blockDim.x + threadIdx.x;
    if (i >= O * 384) return;
    int o = i / 384, k = i % 384;
    float v;
    if (k < 128)      v = W[o * 384 + k] - W[o * 384 + 256 + k];
    else if (k < 256) v = W[o * 384 + k];
    else              v = 2.0f * W[o * 384 + k];
    Wp[i] = f2bf(v);
}

// -------- x (f32) -> bf16, 4 elems per thread ----------

__global__ void cvt_kernel(const float* __restrict__ x, u16* __restrict__ y) {
    int i = blockIdx.x * blockDim.x + threadIdx.x;
    if (i >= N_NODES * FEAT / 4) return;
    float4 v = ((const float4*)x)[i];
    ushort4 o;
    o.x = f2bf(v.x); o.y = f2bf(v.y); o.z = f2bf(v.z); o.w = f2bf(v.w);
    ((ushort4*)y)[i] = o;
}

// -------- DMA-staged row gather -------------------------------------------
// One wave computes one output row. Chunks of <=CAP edges are DMA'd into the
// wave's private LDS staging buffer (global_load_lds: 4 rows per instr, all
// issued back-to-back -> up to 6 KB in flight), then reduced from LDS.
// lane = g*16+f (g: edge slot in quad, f: feature group of 8). Result acc[8]
// is the full row sum, replicated across g after the shfl reduction.

__device__ __forceinline__ void gather_one_row(const int2* __restrict__ ecw,
                                               const u16* __restrict__ X,
                                               u16* sbuf, int s, int e,
                                               int lane, int g, int f, float* acc) {
#pragma unroll
    for (int j = 0; j < 8; ++j) acc[j] = 0.f;
    for (int cs = s; cs < e; cs += CAP) {
        int n = min(e - cs, CAP);
        int npad = (n + 3) & ~3;
        int2 cw = make_int2(0, 0);
        if (lane < n) cw = ecw[cs + lane];          // meta: one coalesced load/chunk
        int   call = cw.x;
        float wall = __int_as_float(cw.y);
        for (int k = 0; k < npad; k += 4) {          // issue all DMAs back-to-back
            int col = __shfl(call, k + g);
            dma16(X + (size_t)col * FEAT + f * 8, sbuf + k * FEAT);
        }
        __builtin_amdgcn_s_waitcnt(0x0F70);          // vmcnt(0): DMA drained
        for (int k = 0; k < npad; k += 4) {
            float wj = __shfl(wall, k + g);
            bf16x8 xv = *(const bf16x8*)(sbuf + (k + g) * FEAT + f * 8);
#pragma unroll
            for (int j = 0; j < 8; ++j) acc[j] += wj * bf2f((u16)xv[j]);
        }
    }
#pragma unroll
    for (int j = 0; j < 8; ++j) {
        acc[j] += __shfl_xor(acc[j], 16);
        acc[j] += __shfl_xor(acc[j], 32);
    }
}

// -------- SpMM: Y[r,:] = sum_e w_e * X[col_e,:]  (4 rows per wave) --------

__global__ __launch_bounds__(256) void spmm_kernel(const int* __restrict__ row_ptr,
                                                   const int2* __restrict__ ecw,
                                                   const u16* __restrict__ X,
                                                   u16* __restrict__ Y) {
    __shared__ __align__(16) u16 stage[4 * CAP * FEAT];   // 24 KB: 6 KB per wave
    int wid = __builtin_amdgcn_readfirstlane(threadIdx.x) >> 6;
    int lane = threadIdx.x & 63;
    int g = lane >> 4, f = lane & 15;
    u16* sbuf = stage + wid * CAP * FEAT;
    int r0 = blockIdx.x * 16 + wid * 4;                   // 16 rows/block

    for (int y = 0; y < 4; ++y) {
        int rr = r0 + y;
        int s = row_ptr[rr], e = row_ptr[rr + 1];
        float acc[8];
        gather_one_row(ecw, X, sbuf, s, e, lane, g, f, acc);
        if (g == 0) {
            u16 tmp[8];
#pragma unroll
            for (int j = 0; j < 8; ++j) tmp[j] = f2bf(acc[j]);
            *(bf16x8*)(Y + (size_t)rr * FEAT + f * 8) = *(const bf16x8*)tmp;
        }
    }
}

// ------- fused: one block = one 16-row tile. Phase 1: 4 waves DMA-gather 4 s2
//         rows each into the shared sT tile. Phase 2: each wave computes O/64
//         column-tiles of out = act( H@W0' + T1@W1' + s2@W2' + b [+H] ).

template <int O, bool RELU, bool RES, bool OUT_F32>
__global__ __launch_bounds__(256) void fused_gemm_kernel(const int* __restrict__ row_ptr,
                                                         const int2* __restrict__ ecw,
                                                         const u16* __restrict__ H,
                                                         const u16* __restrict__ T1,
                                                         const u16* __restrict__ Wp,
                                                         const float* __restrict__ bias,
                                                         void* __restrict__ outv) {
    __shared__ __align__(16) u16 stage[4 * CAP * FEAT];   // 24 KB staging
    __shared__ __align__(16) u16 sT[16 * LDS_PITCH];      // 4.25 KB s2 tile
    int wid = __builtin_amdgcn_readfirstlane(threadIdx.x) >> 6;
    int lane = threadIdx.x & 63;
    int g = lane >> 4, f = lane & 15;
    u16* sbuf = stage + wid * CAP * FEAT;
    int m0 = blockIdx.x * 16;                             // N_NODES % 16 == 0

    // Phase 1: wave wid gathers s2 rows y = wid*4 .. wid*4+3
    for (int y = wid * 4; y < wid * 4 + 4; ++y) {
        int rr = m0 + y;
        int s = row_ptr[rr], e = row_ptr[rr + 1];
        float acc[8];
        gather_one_row(ecw, T1, sbuf, s, e, lane, g, f, acc);
        if (g == 0) {
            u16 tmp[8];
#pragma unroll
            for (int j = 0; j < 8; ++j) tmp[j] = f2bf(acc[j]);
            *(bf16x8*)(sT + y * LDS_PITCH + f * 8) = *(const bf16x8*)tmp;
        }
    }
    __syncthreads();

    // Phase 2: MFMA over K = [H(128) | T1(128) | s2(128)]; wave wid owns
    // column-tiles t = wid*NW .. wid*NW+NW-1
    int r = f, q = g;
    constexpr int NT = O / 16;
    constexpr int NW = NT / 4;          // 2 for O=128, 1 for O=64
    f32x4 acc[NW];
#pragma unroll
    for (int t = 0; t < NW; ++t) acc[t] = (f32x4){0.f, 0.f, 0.f, 0.f};

#pragma unroll
    for (int kk = 0; kk < 12; ++kk) {
        bf16x8 af;
        if (kk < 4)
            af = *(const bf16x8*)(H + (size_t)(m0 + r) * FEAT + kk * 32 + q * 8);
        else if (kk < 8)
            af = *(const bf16x8*)(T1 + (size_t)(m0 + r) * FEAT + (kk - 4) * 32 + q * 8);
        else
            af = *(const bf16x8*)(sT + r * LDS_PITCH + (kk - 8) * 32 + q * 8);
#pragma unroll
        for (int t = 0; t < NW; ++t) {
            int ot = wid * NW + t;
            bf16x8 bfr = *(const bf16x8*)(Wp + (size_t)(ot * 16 + r) * 384 + kk * 32 + q * 8);
            acc[t] = __builtin_amdgcn_mfma_f32_16x16x32_bf16(af, bfr, acc[t], 0, 0, 0);
        }
    }

#pragma unroll
    for (int t = 0; t < NW; ++t) {
        int col = (wid * NW + t) * 16 + r;
        float bv = bias[col];
#pragma unroll
        for (int i = 0; i < 4; ++i) {
            int row = m0 + q * 4 + i;
            float v = acc[t][i] + bv;
            if (RES)  v += bf2f(H[(size_t)row * FEAT + col]);
            if (RELU) v = fmaxf(v, 0.f);
            if (OUT_F32) ((float*)outv)[(size_t)row * O + col] = v;
            else         ((u16*)outv)[(size_t)row * O + col] = f2bf(v);
        }
    }
}

// ---------------- launcher ----------------

static inline size_t align_up(size_t x) { return (x + 255) & ~(size_t)255; }

extern "C" void kernel_launch(void* const* d_in, const int* in_sizes, int n_in,
                              void* d_out, int out_size, void* d_ws, size_t ws_size,
                              hipStream_t stream) {
    const float* x     = (const float*)d_in[0];
    const int*   ei    = (const int*)d_in[1];
    const float* ew    = (const float*)d_in[2];
    const float* W_in  = (const float*)d_in[3];
    const float* b_in  = (const float*)d_in[4];
    const float* W_h1  = (const float*)d_in[5];
    const float* b_h1  = (const float*)d_in[6];
    const float* W_h2  = (const float*)d_in[7];
    const float* b_h2  = (const float*)d_in[8];
    const float* W_out = (const float*)d_in[9];
    const float* b_out = (const float*)d_in[10];

    const int* rows = ei;
    const int* cols = ei + N_EDGES;

    // workspace layout — ~65.2 MB (proven budget)
    char* w = (char*)d_ws;
    size_t off = 0;
    int* counts = (int*)(w + off);            off = align_up(off + (size_t)N_NODES * 4);   // reused as fill
    int* row_ptr= (int*)(w + off);            off = align_up(off + (size_t)(N_NODES + 1) * 4);
    int* bsum   = (int*)(w + off);            off = align_up(off + 512 * 4);
    int2* ecw   = (int2*)(w + off);           off = align_up(off + (size_t)N_EDGES * 8);
    u16* t1     = (u16*)(w + off);            off = align_up(off + (size_t)N_NODES * FEAT * 2);
    u16* h      = (u16*)(w + off);            off = align_up(off + (size_t)N_NODES * FEAT * 2);
    u16* Wp_in  = (u16*)(w + off);            off = align_up(off + (size_t)128 * 384 * 2);
    u16* Wp_h1  = (u16*)(w + off);            off = align_up(off + (size_t)128 * 384 * 2);
    u16* Wp_h2  = (u16*)(w + off);            off = align_up(off + (size_t)128 * 384 * 2);
    u16* Wp_out = (u16*)(w + off);            off = align_up(off + (size_t)64 * 384 * 2);

    hipMemsetAsync(counts, 0, (size_t)N_NODES * 4, stream);

    // weight prep + input conversion
    prep_w_kernel<<<(128 * 384 + 255) / 256, 256, 0, stream>>>(W_in, Wp_in, 128);
    prep_w_kernel<<<(128 * 384 + 255) / 256, 256, 0, stream>>>(W_h1, Wp_h1, 128);
    prep_w_kernel<<<(128 * 384 + 255) / 256, 256, 0, stream>>>(W_h2, Wp_h2, 128);
    prep_w_kernel<<<(64 * 384 + 255) / 256, 256, 0, stream>>>(W_out, Wp_out, 64);
    cvt_kernel<<<(N_NODES * FEAT / 4 + 255) / 256, 256, 0, stream>>>(x, h);

    // CSR build (counting sort)
    hist_kernel<<<N_EDGES / 256, 256, 0, stream>>>(rows, counts);
    reduce_counts_kernel<<<NB_SCAN, 256, 0, stream>>>(counts, bsum);
    scan_bsums_kernel<<<1, 512, 0, stream>>>(bsum, row_ptr);
    write_rowptr_kernel<<<NB_SCAN, 256, 0, stream>>>(counts, bsum, row_ptr);  // zeroes counts -> fill
    scatter_kernel<<<N_EDGES / 256, 256, 0, stream>>>(rows, cols, ew, row_ptr, counts, ecw);

    const int grid16 = N_NODES / 16;   // 6250 blocks: 16 rows per 256-thread block

    // Layer 1: h = relu(cheb(x))    (x pre-converted to bf16 in h; in-place row-local GEMM)
    spmm_kernel<<<grid16, 256, 0, stream>>>(row_ptr, ecw, h, t1);
    fused_gemm_kernel<128, true, false, false><<<grid16, 256, 0, stream>>>(
        row_ptr, ecw, h, t1, Wp_in, b_in, h);

    // Layer 2: h = relu(cheb(h) + h)
    spmm_kernel<<<grid16, 256, 0, stream>>>(row_ptr, ecw, h, t1);
    fused_gemm_kernel<128, true, true, false><<<grid16, 256, 0, stream>>>(
        row_ptr, ecw, h, t1, Wp_h1, b_h1, h);

    // Layer 3: h = relu(cheb(h) + h)
    spmm_kernel<<<grid16, 256, 0, stream>>>(row_ptr, ecw, h, t1);
    fused_gemm_kernel<128, true, true, false><<<grid16, 256, 0, stream>>>(
        row_ptr, ecw, h, t1, Wp_h2, b_h2, h);

    // Layer 4: out = cheb(h)   (O = 64, f32 output, no relu/residual)
    spmm_kernel<<<grid16, 256, 0, stream>>>(row_ptr, ecw, h, t1);
    fused_gemm_kernel<64, false, false, true><<<grid16, 256, 0, stream>>>(
        row_ptr, ecw, h, t1, Wp_out, b_out, d_out);
}